// Round 9
// baseline (17.730 us; speedup 1.0000x reference)
//
#include <hip/hip_runtime.h>
#include <math.h>

#define LN2_INV  1.4426950408889634f   // 1/ln(2)
#define INV_2PI  0.15915494309189535f  // 1/(2*pi)
#define NH 32
// L = 4096 = 64*64, l = 64a + b.  Per head: out[a][b] = sum_{k=0}^{63} A[a][k]*B[k][b]
//   A[a][2n]=Pr[n][a], A[a][2n+1]=Pi[n][a],  P = 2*coef*S^(64a)
//   B[2n][b]=Qr[n][b], B[2n+1][b]=-Qi[n][b], Q = S^b,  S = exp(dtA)
// == Re( sum_n 2*coef*S^(64a+b) )  (exact reformulation; verified in r8)
//
// One block per head, 4 waves.
// Phase A: 32 lanes -> per-n consts (libm).
// Phase B: 256 threads build bf16 hi/lo operand planes in LDS.
//          thread t: a(=b) = t&63, n-block nb=(t>>6)*8 -> 8 P + 8 Q evals,
//          packed as two kslots -> 8x ds_write_b128, conflict-free.
// Phase C: wave w -> C-tile (R=w>>1, Cc=w&1); per K-step 4x ds_read_b128
//          (contiguous, conflict-free) + 3 MFMA (AhBh + AhBl + AlBh).
// Plane layout: s?[ks][row][e], element (row, k) at ks=k>>3, e=k&7; frag
// read lane: [2s+hi][32*blk + (lane&31)] -> k = 16s+8hi+e (same mapping
// that passed in round 8).

typedef float f32x16 __attribute__((ext_vector_type(16)));
typedef short bf16x8 __attribute__((ext_vector_type(8)));

__device__ __forceinline__ unsigned short bf16_rne(float x) {
    unsigned u = __float_as_uint(x);
    unsigned r = u + 0x7FFFu + ((u >> 16) & 1u);
    return (unsigned short)(r >> 16);
}
__device__ __forceinline__ float bf16f(unsigned short b) {
    return __uint_as_float(((unsigned)b) << 16);
}

__global__ __launch_bounds__(256, 4) void s4d_mfma_lds(
    const float* __restrict__ log_dt,
    const float* __restrict__ C,
    const float* __restrict__ log_A_real,
    const float* __restrict__ A_imag,
    float* __restrict__ out)
{
    __shared__ __align__(16) short sAh[8][64][8];
    __shared__ __align__(16) short sAl[8][64][8];
    __shared__ __align__(16) short sBh[8][64][8];
    __shared__ __align__(16) short sBl[8][64][8];
    __shared__ float4 sC[NH];   // {log2|S|/step, rev/step, 2*coef_r, 2*coef_i}

    const int h = blockIdx.x;
    const int t = threadIdx.x;

    // ---- Phase A: per-n constants (accurate libm, lanes 0..31) ----
    if (t < NH) {
        const int n = t;
        const float dt = expf(log_dt[h]);
        const float Ar = -expf(log_A_real[h * NH + n]);
        const float Ai = A_imag[h * NH + n];
        const float xr = Ar * dt;            // Re(dtA)
        const float xi = Ai * dt;            // Im(dtA)
        const float em = expf(xr);
        const float cs = cosf(xi);
        const float sn = sinf(xi);
        const float sr = em * cs;            // Re(S)
        const float si = em * sn;            // Im(S)
        const float er = sr - 1.0f;          // S-1
        const float ei = si;
        const float inv = 1.0f / fmaf(Ar, Ar, Ai * Ai);
        const float tr = fmaf(er, Ar,  ei * Ai) * inv;   // (S-1)/A
        const float ti = fmaf(ei, Ar, -er * Ai) * inv;
        const float c0 = C[(h * NH + n) * 2 + 0];
        const float c1 = C[(h * NH + n) * 2 + 1];
        const float cr = 2.0f * fmaf(c0, tr, -c1 * ti);  // 2*coef_r
        const float ci = 2.0f * fmaf(c0, ti,  c1 * tr);  // 2*coef_i
        sC[n] = make_float4(xr * LN2_INV, xi * INV_2PI, cr, ci);
    }
    __syncthreads();

    // ---- Phase B: build operand planes ----
    {
        const int a  = t & 63;              // row for A / col for B
        const int nb = (t >> 6) * 8;        // this thread's 8 n-values
        const float fa = (float)(64 * a);   // P exponent arg
        const float fb = (float)a;          // Q exponent arg

#pragma unroll
        for (int g = 0; g < 2; ++g) {       // two kslots of 4 n each
            const int ks = (nb >> 2) + g;
            bf16x8 Ah8, Al8, Bh8, Bl8;
#pragma unroll
            for (int j = 0; j < 4; ++j) {
                const int n = nb + 4 * g + j;
                const float4 q = sC[n];     // wave-uniform n -> broadcast read
                // P = 2*coef * S^(64a)
                const float eP  = __builtin_amdgcn_exp2f(q.x * fa);
                const float thP = __builtin_amdgcn_fractf(q.y * fa);
                const float kr  = eP * __builtin_amdgcn_cosf(thP);
                const float ki  = eP * __builtin_amdgcn_sinf(thP);
                const float Pr  = fmaf(q.z, kr, -q.w * ki);
                const float Pi  = fmaf(q.z, ki,  q.w * kr);
                // Q = S^b  (store Qr, -Qi)
                const float eQ  = __builtin_amdgcn_exp2f(q.x * fb);
                const float thQ = __builtin_amdgcn_fractf(q.y * fb);
                const float Qr  = eQ * __builtin_amdgcn_cosf(thQ);
                const float Qmi = -(eQ * __builtin_amdgcn_sinf(thQ));
                // bf16 hi/lo splits
                const unsigned short prh = bf16_rne(Pr);
                const unsigned short pih = bf16_rne(Pi);
                const unsigned short qrh = bf16_rne(Qr);
                const unsigned short qih = bf16_rne(Qmi);
                Ah8[2 * j + 0] = (short)prh;
                Ah8[2 * j + 1] = (short)pih;
                Al8[2 * j + 0] = (short)bf16_rne(Pr - bf16f(prh));
                Al8[2 * j + 1] = (short)bf16_rne(Pi - bf16f(pih));
                Bh8[2 * j + 0] = (short)qrh;
                Bh8[2 * j + 1] = (short)qih;
                Bl8[2 * j + 0] = (short)bf16_rne(Qr - bf16f(qrh));
                Bl8[2 * j + 1] = (short)bf16_rne(Qmi - bf16f(qih));
            }
            *reinterpret_cast<bf16x8*>(&sAh[ks][a][0]) = Ah8;
            *reinterpret_cast<bf16x8*>(&sAl[ks][a][0]) = Al8;
            *reinterpret_cast<bf16x8*>(&sBh[ks][a][0]) = Bh8;
            *reinterpret_cast<bf16x8*>(&sBl[ks][a][0]) = Bl8;
        }
    }
    __syncthreads();

    // ---- Phase C: per-wave 32x32 C-tile via MFMA ----
    const int w    = t >> 6;
    const int R    = w >> 1;        // row block
    const int Cc   = w & 1;         // col block
    const int lane = t & 63;
    const int c    = lane & 31;
    const int hi   = lane >> 5;

    f32x16 acc;
#pragma unroll
    for (int i = 0; i < 16; ++i) acc[i] = 0.0f;

#pragma unroll
    for (int s = 0; s < 4; ++s) {
        const int ks = 2 * s + hi;
        const bf16x8 a_h = *reinterpret_cast<const bf16x8*>(&sAh[ks][R * 32 + c][0]);
        const bf16x8 a_l = *reinterpret_cast<const bf16x8*>(&sAl[ks][R * 32 + c][0]);
        const bf16x8 b_h = *reinterpret_cast<const bf16x8*>(&sBh[ks][Cc * 32 + c][0]);
        const bf16x8 b_l = *reinterpret_cast<const bf16x8*>(&sBl[ks][Cc * 32 + c][0]);
        acc = __builtin_amdgcn_mfma_f32_32x32x16_bf16(a_h, b_h, acc, 0, 0, 0);
        acc = __builtin_amdgcn_mfma_f32_32x32x16_bf16(a_h, b_l, acc, 0, 0, 0);
        acc = __builtin_amdgcn_mfma_f32_32x32x16_bf16(a_l, b_h, acc, 0, 0, 0);
    }

    // ---- store: C/D layout col=lane&31, row=(r&3)+8*(r>>2)+4*(lane>>5) ----
    float* op = out + (size_t)h * 4096;
#pragma unroll
    for (int r = 0; r < 16; ++r) {
        const int row = (r & 3) + 8 * (r >> 2) + 4 * hi;
        const int a   = R * 32 + row;
        op[a * 64 + Cc * 32 + c] = acc[r];
    }
}

extern "C" void kernel_launch(void* const* d_in, const int* in_sizes, int n_in,
                              void* d_out, int out_size, void* d_ws, size_t ws_size,
                              hipStream_t stream)
{
    const float* log_dt     = (const float*)d_in[0];
    const float* C          = (const float*)d_in[1];
    const float* log_A_real = (const float*)d_in[2];
    const float* A_imag     = (const float*)d_in[3];
    float* out = (float*)d_out;

    const int H = in_sizes[0];          // 1024; L = out_size/H = 4096 = 64*64
    hipLaunchKernelGGL(s4d_mfma_lds, dim3(H), dim3(256), 0, stream,
                       log_dt, C, log_A_real, A_imag, out);
}